// Round 6
// baseline (1791.938 us; speedup 1.0000x reference)
//
#include <hip/hip_runtime.h>
#include <hip/hip_fp16.h>

// DiffusionConvolution: out[b,n,o] = bias[o] + sum_{s,k,d} (A_s^k x0)[n,(d,b)] * W[(s*3+k)*64+d, o]
// B=32, N=20000, D=OUT=64, K=2, E=640000 per support.
//
// R9 structure (fp16 end-to-end X pipeline, 4-lane/row SpMM):
//   X0/X1/X2 fp16 BLOCKED layout X[b][n][64] — per-b slab 2.56 MB < 4 MB L2, XCD-pinned sweep.
//   spmm_c: thread owns (row n, 32 B feat slice: uint4 q and q+4); 2-edge unroll,
//     4x16B gathers in flight; fp16 unpack folds to v_fma_mix (fpext-fma combine).
//     R8's 8-lane version spent ~54% VALU on redundant euv loads + addressing + cvt.
//   proj_mfma: mfma_f32_16x16x32_f16. W fp32 -> fp16 hi + fp16 residual (22-bit mantissa);
//     j=0 A from fp32 inp split the same way (3 MFMAs); j=1,2 X fp16 staged directly
//     (2 MFMAs, zero staging conversion). LDS 16B-block-index XOR row&7 swizzle.
// Workspace: X1 82 + X2 82 + euv 5.1 + ptr/counts 0.2 + Wt 0.2 + X0 82 = ~252 MB.

constexpr int B = 32;
constexpr int D = 64;
constexpr int C = B * D;   // 2048 features per node

typedef _Float16 f16x8 __attribute__((ext_vector_type(8)));
typedef float f32x4 __attribute__((ext_vector_type(4)));

__device__ __forceinline__ void fma4(float4& a, float s, const float4 b) {
  a.x = fmaf(s, b.x, a.x);
  a.y = fmaf(s, b.y, a.y);
  a.z = fmaf(s, b.z, a.z);
  a.w = fmaf(s, b.w, a.w);
}

__device__ __forceinline__ unsigned pkh(float a, float b) {
  union { __half2 h; unsigned u; } c;
  c.h = __floats2half2_rn(a, b);
  return c.u;
}

// fp32 pair -> packed fp16 hi + packed fp16 residual
__device__ __forceinline__ unsigned pkh_split(float a, float b, unsigned& lo) {
  __half ha = __float2half_rn(a), hb = __float2half_rn(b);
  float ra = a - __half2float(ha), rb = b - __half2float(hb);
  __half la = __float2half_rn(ra), lb = __float2half_rn(rb);
  lo = (unsigned)__half_as_ushort(la) | ((unsigned)__half_as_ushort(lb) << 16);
  return (unsigned)__half_as_ushort(ha) | ((unsigned)__half_as_ushort(hb) << 16);
}

// acc[8] += v * (8 fp16 in u) — fpext+fma folds to v_fma_mix_f32
__device__ __forceinline__ void fmah8(float (&a)[8], float v, uint4 u) {
  union { uint4 u; __half h[8]; } w; w.u = u;
#pragma unroll
  for (int i = 0; i < 8; ++i) a[i] = fmaf(v, __half2float(w.h[i]), a[i]);
}

// ---------------- CSR build ----------------

__global__ __launch_bounds__(256) void hist_k(const int* __restrict__ rows,
                                              int* __restrict__ counts, int E) {
  int e = blockIdx.x * 256 + threadIdx.x;
  if (e < E) atomicAdd(&counts[rows[e]], 1);
}

// scan + zero counts (counts reused as fill cursor; saves a memset dispatch)
__global__ __launch_bounds__(256) void scan_k(int* __restrict__ counts,
                                              int* __restrict__ row_ptr, int N) {
  __shared__ int part[256];
  int t = threadIdx.x;
  int chunk = (N + 255) >> 8;
  int lo = t * chunk; if (lo > N) lo = N;
  int hi = lo + chunk; if (hi > N) hi = N;
  int s = 0;
  for (int i = lo; i < hi; ++i) s += counts[i];
  part[t] = s;
  __syncthreads();
  for (int off = 1; off < 256; off <<= 1) {
    int x = (t >= off) ? part[t - off] : 0;
    __syncthreads();
    part[t] += x;
    __syncthreads();
  }
  int run = part[t] - s;
  for (int i = lo; i < hi; ++i) {
    row_ptr[i] = run; run += counts[i]; counts[i] = 0;
  }
  if (t == 255) row_ptr[N] = part[255];
}

__global__ __launch_bounds__(256) void fill_k(const int* __restrict__ rows,
                                              const int* __restrict__ cols,
                                              const float* __restrict__ vals,
                                              const int* __restrict__ row_ptr,
                                              int* __restrict__ cursor,
                                              uint2* __restrict__ euv, int E) {
  int e = blockIdx.x * 256 + threadIdx.x;
  if (e < E) {
    int r = rows[e];
    int pos = row_ptr[r] + atomicAdd(&cursor[r], 1);
    euv[pos] = make_uint2((unsigned)cols[e], __float_as_uint(vals[e]));
  }
}

// ---------------- wt_prep: W fp32 [384][64] -> Wt hi/lo fp16 [6][64 o][64 k] ----------------

__global__ __launch_bounds__(256) void wt_prep(const float* __restrict__ W,
                                               ushort* __restrict__ Whi,
                                               ushort* __restrict__ Wlo) {
  int idx = blockIdx.x * 256 + threadIdx.x;
  if (idx >= 384 * 64) return;
  int g = idx >> 6, o = idx & 63;            // g = s*192 + j*64 + k
  int s = g / 192, rem = g - s * 192;
  int j = rem >> 6, k = rem & 63;
  float v = W[g * 64 + o];
  __half hh = __float2half_rn(v);
  __half hl = __float2half_rn(v - __half2float(hh));
  int pos = ((s * 3 + j) * 64 + o) * 64 + k;
  Whi[pos] = __half_as_ushort(hh);
  Wlo[pos] = __half_as_ushort(hl);
}

// ---------------- pack_x0: streaming fp32 -> fp16, identical [b][n][d] index ----------------

__global__ __launch_bounds__(256) void pack_x0(const float4* __restrict__ inp4,
                                               uint4* __restrict__ X0u4, long total) {
  long i = (long)blockIdx.x * 256 + threadIdx.x;
  long stride = (long)gridDim.x * 256;
  for (; i < total; i += stride) {
    float4 v0 = inp4[i * 2];
    float4 v1 = inp4[i * 2 + 1];
    X0u4[i] = make_uint4(pkh(v0.x, v0.y), pkh(v0.z, v0.w),
                         pkh(v1.x, v1.y), pkh(v1.z, v1.w));
  }
}

// ---------------- spmm_c: D = A * S, chunked, 4 lanes/row x 32 B ----------------
// Blocked fp16 S[b][n][64]. Block = 64 rows x 4 lanes; thread t: row rg*64+(t>>2),
// slice q = t&3 (owns uint4 q and q+4 -> gather instrs each cover one 64 B line/row).
// Grid 32*RB, RB=ceil(N/64); decode xcd=i&7, c=xcd+8*(j/RB) -> slab L2-resident/XCD.
// No cross-lane ops; 2-edge unroll = 4 gathers + 2 euv loads in flight.

__global__ __launch_bounds__(256) void spmm_c(const uint4* __restrict__ Su4,
                                              const int* __restrict__ row_ptr,
                                              const uint2* __restrict__ euv,
                                              uint4* __restrict__ Du4,
                                              int N, int RB) {
  int i = blockIdx.x;
  int x = i & 7, jj = i >> 3;
  int cg = jj / RB, rg = jj - cg * RB;
  int c = x + 8 * cg;                      // chunk == batch index b, 0..31
  int t = threadIdx.x;
  int n = rg * 64 + (t >> 2);
  if (n >= N) return;
  int q = t & 3;

  int start = row_ptr[n], end = row_ptr[n + 1];
  const uint4* base = Su4 + (size_t)c * (N * 8) + q;
  float accA[8], accB[8];
#pragma unroll
  for (int k = 0; k < 8; ++k) { accA[k] = 0.f; accB[k] = 0.f; }

  int e = start;
  for (; e + 2 <= end; e += 2) {
    uint2 ev0 = euv[e], ev1 = euv[e + 1];
    const uint4* r0 = base + (size_t)ev0.x * 8;
    const uint4* r1 = base + (size_t)ev1.x * 8;
    uint4 u00 = r0[0], u01 = r0[4];
    uint4 u10 = r1[0], u11 = r1[4];
    float v0 = __uint_as_float(ev0.y), v1 = __uint_as_float(ev1.y);
    fmah8(accA, v0, u00); fmah8(accB, v0, u01);
    fmah8(accA, v1, u10); fmah8(accB, v1, u11);
  }
  if (e < end) {
    uint2 ev = euv[e];
    const uint4* r0 = base + (size_t)ev.x * 8;
    uint4 u0 = r0[0], u1 = r0[4];
    float v = __uint_as_float(ev.y);
    fmah8(accA, v, u0); fmah8(accB, v, u1);
  }

  uint4* dst = Du4 + ((size_t)c * N + n) * 8 + q;
  dst[0] = make_uint4(pkh(accA[0], accA[1]), pkh(accA[2], accA[3]),
                      pkh(accA[4], accA[5]), pkh(accA[6], accA[7]));
  dst[4] = make_uint4(pkh(accB[0], accB[1]), pkh(accB[2], accB[3]),
                      pkh(accB[4], accB[5]), pkh(accB[6], accB[7]));
}

// ---------------- spmm1 (fallback, no-X0 path): fp32 full-row gather, blocked fp16 write ----

__global__ __launch_bounds__(256) void spmm1(const float4* __restrict__ inp4,
                                             const int* __restrict__ row_ptr,
                                             const uint2* __restrict__ euv,
                                             uint2* __restrict__ X1u2, int N) {
  int t = threadIdx.x;
  int n = blockIdx.x;
  float4 acc0 = {0.f, 0.f, 0.f, 0.f};
  float4 acc1 = {0.f, 0.f, 0.f, 0.f};
  int start = row_ptr[n], end = row_ptr[n + 1];
  int b0 = t >> 4;
  const float4* p0 = inp4 + (size_t)b0 * (N * 16) + (t & 15);
  const float4* p1 = inp4 + (size_t)(b0 + 16) * (N * 16) + (t & 15);
  for (int e = start; e < end; ++e) {
    uint2 ev = euv[e];
    float v = __uint_as_float(ev.y);
    fma4(acc0, v, p0[(size_t)ev.x * 16]);
    fma4(acc1, v, p1[(size_t)ev.x * 16]);
  }
  X1u2[((size_t)b0 * N + n) * 16 + (t & 15)] =
      make_uint2(pkh(acc0.x, acc0.y), pkh(acc0.z, acc0.w));
  X1u2[((size_t)(b0 + 16) * N + n) * 16 + (t & 15)] =
      make_uint2(pkh(acc1.x, acc1.y), pkh(acc1.z, acc1.w));
}

// ---------------- proj_mfma: out (+)= inp*W0 + X1*W1 + X2*W2 (+bias) via f16 MFMA ----------
// grid ((N+63)/64, B), 256 threads = 4 waves. Out tile 64n x 64o for batch b.
// mfma_f32_16x16x32_f16, layouts dtype-independent (m89/m121-verified):
//   A frag: lane l holds A[l&15, 8*(l>>4)+e]; B frag: B[8*(l>>4)+e, l&15];
//   C/D: col=l&15, row=(l>>4)*4+reg.
// LDS tiles [64 rows][64 k] fp16, 128 B/row; 16B-block index ^= (row&7).

template <bool ADD>
__global__ __launch_bounds__(256) void proj_mfma(const float4* __restrict__ inp4,
                                                 const uint4* __restrict__ X1u4,
                                                 const uint4* __restrict__ X2u4,
                                                 const ushort* __restrict__ Whi,
                                                 const ushort* __restrict__ Wlo,
                                                 int sj0,   // 3*s
                                                 const float* __restrict__ bias,
                                                 float* __restrict__ out, int N) {
  __shared__ uint4 ldsbuf[2048];       // 32 KB
  char* sAhi = (char*)ldsbuf;          // 8 KB  [64 n][64 k] fp16
  char* sAlo = sAhi + 8192;            // 8 KB  (j==0 only)
  char* sWhi = sAhi + 16384;           // 8 KB  [64 o][64 k] fp16
  char* sWlo = sAhi + 24576;           // 8 KB

  int t = threadIdx.x;
  int lane = t & 63, w = t >> 6;
  int b = blockIdx.y;
  int n0 = blockIdx.x * 64;
  int col = lane & 15, kg = lane >> 4;

  f32x4 acc[4];
  if (ADD) {
#pragma unroll
    for (int c = 0; c < 4; ++c) acc[c] = (f32x4){0.f, 0.f, 0.f, 0.f};
  } else {
#pragma unroll
    for (int c = 0; c < 4; ++c) {
      float bv = bias[c * 16 + col];
      acc[c] = (f32x4){bv, bv, bv, bv};
    }
  }

  for (int j = 0; j < 3; ++j) {
    // ---- stage W slice hi/lo (transposed [o][k], swizzled) ----
    {
      const uint4* srcH = (const uint4*)(Whi + (size_t)(sj0 + j) * 4096);
      const uint4* srcL = (const uint4*)(Wlo + (size_t)(sj0 + j) * 4096);
#pragma unroll
      for (int kk = 0; kk < 2; ++kk) {
        int q = t + 256 * kk;
        int o = q >> 3, x8 = q & 7;
        int doff = o * 128 + ((x8 * 16) ^ ((o & 7) << 4));
        *(uint4*)(sWhi + doff) = srcH[q];
        *(uint4*)(sWlo + doff) = srcL[q];
      }
    }
    // ---- stage A tile ----
    if (j == 0) {
      // inp fp32 -> split fp16 hi+lo
#pragma unroll
      for (int kk = 0; kk < 4; ++kk) {
        int q = t + 256 * kk;
        int r = q >> 4, d4 = q & 15;
        int n = n0 + r;
        float4 v = {0.f, 0.f, 0.f, 0.f};
        if (n < N) v = inp4[((size_t)b * N + n) * 16 + d4];
        unsigned l0, l1;
        unsigned h0 = pkh_split(v.x, v.y, l0);
        unsigned h1 = pkh_split(v.z, v.w, l1);
        int doff = r * 128 + ((d4 * 8) ^ ((r & 7) << 4));
        *(uint2*)(sAhi + doff) = make_uint2(h0, h1);
        *(uint2*)(sAlo + doff) = make_uint2(l0, l1);
      }
    } else {
      const uint4* Xs = (j == 1) ? X1u4 : X2u4;
#pragma unroll
      for (int kk = 0; kk < 2; ++kk) {
        int q = t + 256 * kk;
        int r = q >> 3, x8 = q & 7;
        int n = n0 + r;
        uint4 u = {0u, 0u, 0u, 0u};
        if (n < N) u = Xs[((size_t)b * N + n) * 8 + x8];
        int doff = r * 128 + ((x8 * 16) ^ ((r & 7) << 4));
        *(uint4*)(sAhi + doff) = u;
      }
    }
    __syncthreads();

    // ---- MFMA: K=64 in 2 chunks of 32 ----
#pragma unroll
    for (int kc = 0; kc < 2; ++kc) {
      int kb = kc * 64 + kg * 16;                 // byte offset of this lane's 8 k's
      int arow = w * 16 + col;
      int aoff = arow * 128 + (kb ^ ((arow & 7) << 4));
      f16x8 ah = *(const f16x8*)(sAhi + aoff);
      f16x8 al;
      if (j == 0) al = *(const f16x8*)(sAlo + aoff);
#pragma unroll
      for (int c = 0; c < 4; ++c) {
        int wrow = c * 16 + col;
        int woff = wrow * 128 + (kb ^ ((wrow & 7) << 4));
        f16x8 bh = *(const f16x8*)(sWhi + woff);
        f16x8 bl = *(const f16x8*)(sWlo + woff);
        acc[c] = __builtin_amdgcn_mfma_f32_16x16x32_f16(ah, bh, acc[c], 0, 0, 0);
        acc[c] = __builtin_amdgcn_mfma_f32_16x16x32_f16(ah, bl, acc[c], 0, 0, 0);
        if (j == 0)
          acc[c] = __builtin_amdgcn_mfma_f32_16x16x32_f16(al, bh, acc[c], 0, 0, 0);
      }
    }
    __syncthreads();
  }

  // ---- store: row = n0 + 16w + 4*kg + reg, col = 16c + (lane&15) ----
  int rbase = n0 + w * 16 + kg * 4;
  size_t obase = (size_t)b * N * 64;
#pragma unroll
  for (int c = 0; c < 4; ++c) {
#pragma unroll
    for (int r = 0; r < 4; ++r) {
      int row = rbase + r;
      if (row < N) {
        float* op = out + obase + (size_t)row * 64 + c * 16 + col;
        float vv = acc[c][r];
        if (ADD) *op += vv; else *op = vv;
      }
    }
  }
}

// ---------------- launch ----------------

extern "C" void kernel_launch(void* const* d_in, const int* in_sizes, int n_in,
                              void* d_out, int out_size, void* d_ws, size_t ws_size,
                              hipStream_t stream) {
  const float* inp = (const float*)d_in[0];
  const int*   rws[2] = {(const int*)d_in[1], (const int*)d_in[4]};
  const int*   cls[2] = {(const int*)d_in[2], (const int*)d_in[5]};
  const float* vls[2] = {(const float*)d_in[3], (const float*)d_in[6]};
  const float* W    = (const float*)d_in[7];
  const float* bias = (const float*)d_in[8];
  float* out = (float*)d_out;

  const int N = in_sizes[0] / C;          // 20000
  const int Emax = (in_sizes[1] > in_sizes[4]) ? in_sizes[1] : in_sizes[4];

  // workspace layout: X1, X2, euv, ptr/counts, Wt hi/lo, then X0 fp16 tail (guarded)
  char* ws = (char*)d_ws;
  size_t rowBytes = (size_t)C * 2;                        // 4096 B/node fp16
  ushort* X1 = (ushort*)ws;                size_t off = (size_t)N * rowBytes;  // 81.92 MB
  ushort* X2 = (ushort*)(ws + off);        off += (size_t)N * rowBytes;        // 81.92 MB
  uint2* euv = (uint2*)(ws + off);         off += (size_t)Emax * 8;
  int*   row_ptr = (int*)(ws + off);       off += (size_t)(N + 1) * 4;
  off = (off + 255) & ~(size_t)255;
  int*   counts = (int*)(ws + off);        off += (size_t)N * 4;
  off = (off + 255) & ~(size_t)255;
  ushort* Wt_hi = (ushort*)(ws + off);     off += (size_t)6 * 64 * 64 * 2;     // 48 KB
  ushort* Wt_lo = (ushort*)(ws + off);     off += (size_t)6 * 64 * 64 * 2;     // 48 KB
  off = (off + 255) & ~(size_t)255;
  ushort* X0 = (ushort*)(ws + off);        off += (size_t)N * rowBytes;        // 81.92 MB
  const bool useX0 = (ws_size >= off);
  (void)n_in; (void)out_size;

  dim3 gp((N + 63) / 64, B);
  const int RB = (N + 63) / 64;           // rowgroups of 64 (one block each)

  wt_prep<<<96, 256, 0, stream>>>(W, Wt_hi, Wt_lo);
  if (useX0) {
    pack_x0<<<2048, 256, 0, stream>>>((const float4*)inp, (uint4*)X0,
                                      (long)B * N * 8);
  }

  for (int s = 0; s < 2; ++s) {
    const int E = in_sizes[s == 0 ? 1 : 4];

    hipMemsetAsync(counts, 0, (size_t)N * 4, stream);
    hist_k<<<(E + 255) / 256, 256, 0, stream>>>(rws[s], counts, E);
    scan_k<<<1, 256, 0, stream>>>(counts, row_ptr, N);     // also zeroes counts (cursor)
    fill_k<<<(E + 255) / 256, 256, 0, stream>>>(rws[s], cls[s], vls[s], row_ptr,
                                                counts, euv, E);

    if (useX0) {
      spmm_c<<<32 * RB, 256, 0, stream>>>((const uint4*)X0, row_ptr, euv,
                                          (uint4*)X1, N, RB);
    } else {
      spmm1<<<N, 256, 0, stream>>>((const float4*)inp, row_ptr, euv,
                                   (uint2*)X1, N);
    }
    spmm_c<<<32 * RB, 256, 0, stream>>>((const uint4*)X1, row_ptr, euv,
                                        (uint4*)X2, N, RB);

    if (s == 0) {
      proj_mfma<false><<<gp, 256, 0, stream>>>((const float4*)inp, (const uint4*)X1,
                                               (const uint4*)X2, Wt_hi, Wt_lo, 0,
                                               bias, out, N);
    } else {
      proj_mfma<true><<<gp, 256, 0, stream>>>((const float4*)inp, (const uint4*)X1,
                                              (const uint4*)X2, Wt_hi, Wt_lo, 3,
                                              bias, out, N);
    }
  }
}

// Round 7
// 1472.374 us; speedup vs baseline: 1.2170x; 1.2170x over previous
//
#include <hip/hip_runtime.h>
#include <hip/hip_fp16.h>

// DiffusionConvolution: out[b,n,o] = bias[o] + sum_{s,k,d} (A_s^k x0)[n,(d,b)] * W[(s*3+k)*64+d, o]
// B=32, N=20000, D=OUT=64, K=2, E=640000 per support.
//
// R10 = R9 fp16 pipeline + R8 SpMM geometry (the L2-clean one).
//   X0/X1/X2 fp16 BLOCKED layout X[b][n][64] — per-b slab 2.56 MB < 4 MB XCD-L2.
//   spmm_c: 8 lanes/row (thread owns 16 B slice), 32 rows/block, 4-edge unroll.
//     Window arithmetic: rows-in-flight/XCD = 32 waves/CU * 8 rows/wave * 32 CU = 8k
//     = 41% of chunk -> chunk-boundary overlap is rare -> slab stays L2-resident
//     (R9's 4-lane variant had 82% window -> 2 slabs + euv stream thrashed L2,
//      FETCH 240->573 MB, dur 195->265 µs).
//     fp16 gather unpack folds into v_fma_mix_f32 (no bf16 shift/and ops).
//   proj_mfma: mfma_f32_16x16x32_f16; W fp32 -> fp16 hi + fp16 residual; j=0 A split
//     likewise (3 MFMAs, ~fp32-exact); j=1,2 X fp16 staged directly (2 MFMAs).
// Workspace: X1 82 + X2 82 + euv 5.1 + ptr/counts 0.2 + Wt 0.2 + X0 82 = ~252 MB.

constexpr int B = 32;
constexpr int D = 64;
constexpr int C = B * D;   // 2048 features per node

typedef _Float16 f16x8 __attribute__((ext_vector_type(8)));
typedef float f32x4 __attribute__((ext_vector_type(4)));

__device__ __forceinline__ void fma4(float4& a, float s, const float4 b) {
  a.x = fmaf(s, b.x, a.x);
  a.y = fmaf(s, b.y, a.y);
  a.z = fmaf(s, b.z, a.z);
  a.w = fmaf(s, b.w, a.w);
}

__device__ __forceinline__ unsigned pkh(float a, float b) {
  union { __half2 h; unsigned u; } c;
  c.h = __floats2half2_rn(a, b);
  return c.u;
}

// fp32 pair -> packed fp16 hi + packed fp16 residual
__device__ __forceinline__ unsigned pkh_split(float a, float b, unsigned& lo) {
  __half ha = __float2half_rn(a), hb = __float2half_rn(b);
  float ra = a - __half2float(ha), rb = b - __half2float(hb);
  __half la = __float2half_rn(ra), lb = __float2half_rn(rb);
  lo = (unsigned)__half_as_ushort(la) | ((unsigned)__half_as_ushort(lb) << 16);
  return (unsigned)__half_as_ushort(ha) | ((unsigned)__half_as_ushort(hb) << 16);
}

// acc[8] += v * (8 fp16 in u) — fpext+fma folds to v_fma_mix_f32
__device__ __forceinline__ void fmah8(float (&a)[8], float v, uint4 u) {
  union { uint4 u; __half h[8]; } w; w.u = u;
#pragma unroll
  for (int i = 0; i < 8; ++i) a[i] = fmaf(v, __half2float(w.h[i]), a[i]);
}

// ---------------- CSR build ----------------

__global__ __launch_bounds__(256) void hist_k(const int* __restrict__ rows,
                                              int* __restrict__ counts, int E) {
  int e = blockIdx.x * 256 + threadIdx.x;
  if (e < E) atomicAdd(&counts[rows[e]], 1);
}

// scan + zero counts (counts reused as fill cursor; saves a memset dispatch)
__global__ __launch_bounds__(256) void scan_k(int* __restrict__ counts,
                                              int* __restrict__ row_ptr, int N) {
  __shared__ int part[256];
  int t = threadIdx.x;
  int chunk = (N + 255) >> 8;
  int lo = t * chunk; if (lo > N) lo = N;
  int hi = lo + chunk; if (hi > N) hi = N;
  int s = 0;
  for (int i = lo; i < hi; ++i) s += counts[i];
  part[t] = s;
  __syncthreads();
  for (int off = 1; off < 256; off <<= 1) {
    int x = (t >= off) ? part[t - off] : 0;
    __syncthreads();
    part[t] += x;
    __syncthreads();
  }
  int run = part[t] - s;
  for (int i = lo; i < hi; ++i) {
    row_ptr[i] = run; run += counts[i]; counts[i] = 0;
  }
  if (t == 255) row_ptr[N] = part[255];
}

__global__ __launch_bounds__(256) void fill_k(const int* __restrict__ rows,
                                              const int* __restrict__ cols,
                                              const float* __restrict__ vals,
                                              const int* __restrict__ row_ptr,
                                              int* __restrict__ cursor,
                                              uint2* __restrict__ euv, int E) {
  int e = blockIdx.x * 256 + threadIdx.x;
  if (e < E) {
    int r = rows[e];
    int pos = row_ptr[r] + atomicAdd(&cursor[r], 1);
    euv[pos] = make_uint2((unsigned)cols[e], __float_as_uint(vals[e]));
  }
}

// ---------------- wt_prep: W fp32 [384][64] -> Wt hi/lo fp16 [6][64 o][64 k] ----------------

__global__ __launch_bounds__(256) void wt_prep(const float* __restrict__ W,
                                               ushort* __restrict__ Whi,
                                               ushort* __restrict__ Wlo) {
  int idx = blockIdx.x * 256 + threadIdx.x;
  if (idx >= 384 * 64) return;
  int g = idx >> 6, o = idx & 63;            // g = s*192 + j*64 + k
  int s = g / 192, rem = g - s * 192;
  int j = rem >> 6, k = rem & 63;
  float v = W[g * 64 + o];
  __half hh = __float2half_rn(v);
  __half hl = __float2half_rn(v - __half2float(hh));
  int pos = ((s * 3 + j) * 64 + o) * 64 + k;
  Whi[pos] = __half_as_ushort(hh);
  Wlo[pos] = __half_as_ushort(hl);
}

// ---------------- pack_x0: streaming fp32 -> fp16, identical [b][n][d] index ----------------

__global__ __launch_bounds__(256) void pack_x0(const float4* __restrict__ inp4,
                                               uint4* __restrict__ X0u4, long total) {
  long i = (long)blockIdx.x * 256 + threadIdx.x;
  long stride = (long)gridDim.x * 256;
  for (; i < total; i += stride) {
    float4 v0 = inp4[i * 2];
    float4 v1 = inp4[i * 2 + 1];
    X0u4[i] = make_uint4(pkh(v0.x, v0.y), pkh(v0.z, v0.w),
                         pkh(v1.x, v1.y), pkh(v1.z, v1.w));
  }
}

// ---------------- spmm_c: D = A * S, chunked, 8 lanes/row x 16 B ----------------
// Blocked fp16 S[b][n][64]. Block = 32 rows x 8 lanes; thread t: row rg*32+(t>>3),
// uint4 slice q = t&7. Grid 32*RB, RB=ceil(N/32); decode xcd=i&7, c=xcd+8*(j/RB)
// -> chunk slab (2.56 MB) L2-resident per XCD, 41% concurrency window (no thrash).
// No cross-lane ops; 4-edge unroll = 4 x 16 B gathers + euv in flight.

__global__ __launch_bounds__(256) void spmm_c(const uint4* __restrict__ Su4,
                                              const int* __restrict__ row_ptr,
                                              const uint2* __restrict__ euv,
                                              uint4* __restrict__ Du4,
                                              int N, int RB) {
  int i = blockIdx.x;
  int x = i & 7, jj = i >> 3;
  int cg = jj / RB, rg = jj - cg * RB;
  int c = x + 8 * cg;                      // chunk == batch index b, 0..31
  int t = threadIdx.x;
  int n = rg * 32 + (t >> 3);
  if (n >= N) return;
  int q = t & 7;

  int start = row_ptr[n], end = row_ptr[n + 1];
  const uint4* base = Su4 + (size_t)c * (N * 8) + q;
  float acc[8];
#pragma unroll
  for (int k = 0; k < 8; ++k) acc[k] = 0.f;

  int e = start;
  for (; e + 4 <= end; e += 4) {
    uint2 ev0 = euv[e],     ev1 = euv[e + 1];
    uint2 ev2 = euv[e + 2], ev3 = euv[e + 3];
    uint4 u0 = base[(size_t)ev0.x * 8];
    uint4 u1 = base[(size_t)ev1.x * 8];
    uint4 u2 = base[(size_t)ev2.x * 8];
    uint4 u3 = base[(size_t)ev3.x * 8];
    fmah8(acc, __uint_as_float(ev0.y), u0);
    fmah8(acc, __uint_as_float(ev1.y), u1);
    fmah8(acc, __uint_as_float(ev2.y), u2);
    fmah8(acc, __uint_as_float(ev3.y), u3);
  }
  for (; e < end; ++e) {
    uint2 ev = euv[e];
    uint4 u = base[(size_t)ev.x * 8];
    fmah8(acc, __uint_as_float(ev.y), u);
  }

  Du4[((size_t)c * N + n) * 8 + q] = make_uint4(pkh(acc[0], acc[1]), pkh(acc[2], acc[3]),
                                                pkh(acc[4], acc[5]), pkh(acc[6], acc[7]));
}

// ---------------- spmm1 (fallback, no-X0 path): fp32 full-row gather, blocked fp16 write ----

__global__ __launch_bounds__(256) void spmm1(const float4* __restrict__ inp4,
                                             const int* __restrict__ row_ptr,
                                             const uint2* __restrict__ euv,
                                             uint2* __restrict__ X1u2, int N) {
  int t = threadIdx.x;
  int n = blockIdx.x;
  float4 acc0 = {0.f, 0.f, 0.f, 0.f};
  float4 acc1 = {0.f, 0.f, 0.f, 0.f};
  int start = row_ptr[n], end = row_ptr[n + 1];
  int b0 = t >> 4;
  const float4* p0 = inp4 + (size_t)b0 * (N * 16) + (t & 15);
  const float4* p1 = inp4 + (size_t)(b0 + 16) * (N * 16) + (t & 15);
  for (int e = start; e < end; ++e) {
    uint2 ev = euv[e];
    float v = __uint_as_float(ev.y);
    fma4(acc0, v, p0[(size_t)ev.x * 16]);
    fma4(acc1, v, p1[(size_t)ev.x * 16]);
  }
  X1u2[((size_t)b0 * N + n) * 16 + (t & 15)] =
      make_uint2(pkh(acc0.x, acc0.y), pkh(acc0.z, acc0.w));
  X1u2[((size_t)(b0 + 16) * N + n) * 16 + (t & 15)] =
      make_uint2(pkh(acc1.x, acc1.y), pkh(acc1.z, acc1.w));
}

// ---------------- proj_mfma: out (+)= inp*W0 + X1*W1 + X2*W2 (+bias) via f16 MFMA ----------
// grid ((N+63)/64, B), 256 threads = 4 waves. Out tile 64n x 64o for batch b.
// mfma_f32_16x16x32_f16, layouts dtype-independent (m89/m121-verified):
//   A frag: lane l holds A[l&15, 8*(l>>4)+e]; B frag: B[8*(l>>4)+e, l&15];
//   C/D: col=l&15, row=(l>>4)*4+reg.
// LDS tiles [64 rows][64 k] fp16, 128 B/row; 16B-block index ^= (row&7).

template <bool ADD>
__global__ __launch_bounds__(256) void proj_mfma(const float4* __restrict__ inp4,
                                                 const uint4* __restrict__ X1u4,
                                                 const uint4* __restrict__ X2u4,
                                                 const ushort* __restrict__ Whi,
                                                 const ushort* __restrict__ Wlo,
                                                 int sj0,   // 3*s
                                                 const float* __restrict__ bias,
                                                 float* __restrict__ out, int N) {
  __shared__ uint4 ldsbuf[2048];       // 32 KB
  char* sAhi = (char*)ldsbuf;          // 8 KB  [64 n][64 k] fp16
  char* sAlo = sAhi + 8192;            // 8 KB  (j==0 only)
  char* sWhi = sAhi + 16384;           // 8 KB  [64 o][64 k] fp16
  char* sWlo = sAhi + 24576;           // 8 KB

  int t = threadIdx.x;
  int lane = t & 63, w = t >> 6;
  int b = blockIdx.y;
  int n0 = blockIdx.x * 64;
  int col = lane & 15, kg = lane >> 4;

  f32x4 acc[4];
  if (ADD) {
#pragma unroll
    for (int c = 0; c < 4; ++c) acc[c] = (f32x4){0.f, 0.f, 0.f, 0.f};
  } else {
#pragma unroll
    for (int c = 0; c < 4; ++c) {
      float bv = bias[c * 16 + col];
      acc[c] = (f32x4){bv, bv, bv, bv};
    }
  }

  for (int j = 0; j < 3; ++j) {
    // ---- stage W slice hi/lo (transposed [o][k], swizzled) ----
    {
      const uint4* srcH = (const uint4*)(Whi + (size_t)(sj0 + j) * 4096);
      const uint4* srcL = (const uint4*)(Wlo + (size_t)(sj0 + j) * 4096);
#pragma unroll
      for (int kk = 0; kk < 2; ++kk) {
        int q = t + 256 * kk;
        int o = q >> 3, x8 = q & 7;
        int doff = o * 128 + ((x8 * 16) ^ ((o & 7) << 4));
        *(uint4*)(sWhi + doff) = srcH[q];
        *(uint4*)(sWlo + doff) = srcL[q];
      }
    }
    // ---- stage A tile ----
    if (j == 0) {
      // inp fp32 -> split fp16 hi+lo
#pragma unroll
      for (int kk = 0; kk < 4; ++kk) {
        int q = t + 256 * kk;
        int r = q >> 4, d4 = q & 15;
        int n = n0 + r;
        float4 v = {0.f, 0.f, 0.f, 0.f};
        if (n < N) v = inp4[((size_t)b * N + n) * 16 + d4];
        unsigned l0, l1;
        unsigned h0 = pkh_split(v.x, v.y, l0);
        unsigned h1 = pkh_split(v.z, v.w, l1);
        int doff = r * 128 + ((d4 * 8) ^ ((r & 7) << 4));
        *(uint2*)(sAhi + doff) = make_uint2(h0, h1);
        *(uint2*)(sAlo + doff) = make_uint2(l0, l1);
      }
    } else {
      const uint4* Xs = (j == 1) ? X1u4 : X2u4;
#pragma unroll
      for (int kk = 0; kk < 2; ++kk) {
        int q = t + 256 * kk;
        int r = q >> 3, x8 = q & 7;
        int n = n0 + r;
        uint4 u = {0u, 0u, 0u, 0u};
        if (n < N) u = Xs[((size_t)b * N + n) * 8 + x8];
        int doff = r * 128 + ((x8 * 16) ^ ((r & 7) << 4));
        *(uint4*)(sAhi + doff) = u;
      }
    }
    __syncthreads();

    // ---- MFMA: K=64 in 2 chunks of 32 ----
#pragma unroll
    for (int kc = 0; kc < 2; ++kc) {
      int kb = kc * 64 + kg * 16;                 // byte offset of this lane's 8 k's
      int arow = w * 16 + col;
      int aoff = arow * 128 + (kb ^ ((arow & 7) << 4));
      f16x8 ah = *(const f16x8*)(sAhi + aoff);
      f16x8 al;
      if (j == 0) al = *(const f16x8*)(sAlo + aoff);
#pragma unroll
      for (int c = 0; c < 4; ++c) {
        int wrow = c * 16 + col;
        int woff = wrow * 128 + (kb ^ ((wrow & 7) << 4));
        f16x8 bh = *(const f16x8*)(sWhi + woff);
        f16x8 bl = *(const f16x8*)(sWlo + woff);
        acc[c] = __builtin_amdgcn_mfma_f32_16x16x32_f16(ah, bh, acc[c], 0, 0, 0);
        acc[c] = __builtin_amdgcn_mfma_f32_16x16x32_f16(ah, bl, acc[c], 0, 0, 0);
        if (j == 0)
          acc[c] = __builtin_amdgcn_mfma_f32_16x16x32_f16(al, bh, acc[c], 0, 0, 0);
      }
    }
    __syncthreads();
  }

  // ---- store: row = n0 + 16w + 4*kg + reg, col = 16c + (lane&15) ----
  int rbase = n0 + w * 16 + kg * 4;
  size_t obase = (size_t)b * N * 64;
#pragma unroll
  for (int c = 0; c < 4; ++c) {
#pragma unroll
    for (int r = 0; r < 4; ++r) {
      int row = rbase + r;
      if (row < N) {
        float* op = out + obase + (size_t)row * 64 + c * 16 + col;
        float vv = acc[c][r];
        if (ADD) *op += vv; else *op = vv;
      }
    }
  }
}

// ---------------- launch ----------------

extern "C" void kernel_launch(void* const* d_in, const int* in_sizes, int n_in,
                              void* d_out, int out_size, void* d_ws, size_t ws_size,
                              hipStream_t stream) {
  const float* inp = (const float*)d_in[0];
  const int*   rws[2] = {(const int*)d_in[1], (const int*)d_in[4]};
  const int*   cls[2] = {(const int*)d_in[2], (const int*)d_in[5]};
  const float* vls[2] = {(const float*)d_in[3], (const float*)d_in[6]};
  const float* W    = (const float*)d_in[7];
  const float* bias = (const float*)d_in[8];
  float* out = (float*)d_out;

  const int N = in_sizes[0] / C;          // 20000
  const int Emax = (in_sizes[1] > in_sizes[4]) ? in_sizes[1] : in_sizes[4];

  // workspace layout: X1, X2, euv, ptr/counts, Wt hi/lo, then X0 fp16 tail (guarded)
  char* ws = (char*)d_ws;
  size_t rowBytes = (size_t)C * 2;                        // 4096 B/node fp16
  ushort* X1 = (ushort*)ws;                size_t off = (size_t)N * rowBytes;  // 81.92 MB
  ushort* X2 = (ushort*)(ws + off);        off += (size_t)N * rowBytes;        // 81.92 MB
  uint2* euv = (uint2*)(ws + off);         off += (size_t)Emax * 8;
  int*   row_ptr = (int*)(ws + off);       off += (size_t)(N + 1) * 4;
  off = (off + 255) & ~(size_t)255;
  int*   counts = (int*)(ws + off);        off += (size_t)N * 4;
  off = (off + 255) & ~(size_t)255;
  ushort* Wt_hi = (ushort*)(ws + off);     off += (size_t)6 * 64 * 64 * 2;     // 48 KB
  ushort* Wt_lo = (ushort*)(ws + off);     off += (size_t)6 * 64 * 64 * 2;     // 48 KB
  off = (off + 255) & ~(size_t)255;
  ushort* X0 = (ushort*)(ws + off);        off += (size_t)N * rowBytes;        // 81.92 MB
  const bool useX0 = (ws_size >= off);
  (void)n_in; (void)out_size;

  dim3 gp((N + 63) / 64, B);
  const int RB = (N + 31) / 32;           // rowgroups of 32 (one block each)

  wt_prep<<<96, 256, 0, stream>>>(W, Wt_hi, Wt_lo);
  if (useX0) {
    pack_x0<<<2048, 256, 0, stream>>>((const float4*)inp, (uint4*)X0,
                                      (long)B * N * 8);
  }

  for (int s = 0; s < 2; ++s) {
    const int E = in_sizes[s == 0 ? 1 : 4];

    hipMemsetAsync(counts, 0, (size_t)N * 4, stream);
    hist_k<<<(E + 255) / 256, 256, 0, stream>>>(rws[s], counts, E);
    scan_k<<<1, 256, 0, stream>>>(counts, row_ptr, N);     // also zeroes counts (cursor)
    fill_k<<<(E + 255) / 256, 256, 0, stream>>>(rws[s], cls[s], vls[s], row_ptr,
                                                counts, euv, E);

    if (useX0) {
      spmm_c<<<32 * RB, 256, 0, stream>>>((const uint4*)X0, row_ptr, euv,
                                          (uint4*)X1, N, RB);
    } else {
      spmm1<<<N, 256, 0, stream>>>((const float4*)inp, row_ptr, euv,
                                   (uint2*)X1, N);
    }
    spmm_c<<<32 * RB, 256, 0, stream>>>((const uint4*)X1, row_ptr, euv,
                                        (uint4*)X2, N, RB);

    if (s == 0) {
      proj_mfma<false><<<gp, 256, 0, stream>>>((const float4*)inp, (const uint4*)X1,
                                               (const uint4*)X2, Wt_hi, Wt_lo, 0,
                                               bias, out, N);
    } else {
      proj_mfma<true><<<gp, 256, 0, stream>>>((const float4*)inp, (const uint4*)X1,
                                              (const uint4*)X2, Wt_hi, Wt_lo, 3,
                                              bias, out, N);
    }
  }
}